// Round 2
// baseline (968.873 us; speedup 1.0000x reference)
//
#include <hip/hip_runtime.h>

// GeodesicLoss: outputs(B,D) f32, targets(B,D) f32, gamma(B,D,D,D) f32 -> scalar f32
// B=256, D=64, NUM_STEPS=10 (RK2 midpoint integration).
// Strategy: symmetric-pack gamma once (2080/4096 entries per row) into d_ws,
// then 20 accel passes stream the packed copy (136 MB, fits 256MB LLC) with
// fully-unrolled float4 loads (2-row pairs, 16 f4 in flight per wave).

#define NSTEPS 10
#define BATCH 256
#define DIM 64
#define TPB 1024
#define ROWLEN 4096              // DIM*DIM
#define NPACK 2080               // DIM*(DIM+1)/2  (row length, f4-aligned: 520 f4)
#define RBSTRIDE 65              // padded LDS staging stride (bank-conflict-free)
#define WS_ACC_FLOATS 64         // accumulator header in ws (256 B)

__device__ __forceinline__ float waveSum(float v) {
    #pragma unroll
    for (int off = 32; off; off >>= 1) v += __shfl_xor(v, off, 64);
    return v;
}

__global__ void init_ws_kernel(unsigned* ws) {
    if (threadIdx.x < 4) ws[threadIdx.x] = 0u;   // [0]=geo, [1]=euclid, [2]=flag
}

template<int PACKED>
__global__ __launch_bounds__(TPB, 1)
void geo_main_kernel(const float* __restrict__ x0g,
                     const float* __restrict__ x1g,
                     const float* __restrict__ gam,
                     float* __restrict__ ws,
                     float* __restrict__ pack)
{
    __shared__ float vel[DIM];
    __shared__ float mvel[DIM];
    __shared__ float acc[DIM];
    __shared__ float wp[PACKED ? NPACK : ROWLEN];
    __shared__ uchar2 lut[PACKED ? NPACK : 1];            // packed idx -> (j,k)
    __shared__ float rowbuf[PACKED ? 2 * DIM * RBSTRIDE : 1];  // pack staging

    const int b    = blockIdx.x;
    const int t    = threadIdx.x;
    const int wave = t >> 6;
    const int lane = t & 63;
    const float dt = 1.0f / NSTEPS;

    // ---- build (j,k) LUT for packed indexing ----
    if constexpr (PACKED) {
        for (int e = t; e < ROWLEN; e += TPB) {
            int j = e >> 6, k = e & 63;
            if (k >= j) {
                int idx = j * DIM - (j * (j - 1)) / 2 + (k - j);
                lut[idx] = make_uchar2((unsigned char)j, (unsigned char)k);
            }
        }
    }

    // ---- wave 0: initial velocity, trajectory, euclid contribution ----
    float x1r = 0.f, fpPrev = 0.f, fpCur = 0.f, trajr = 0.f;
    if (wave == 0) {
        float x0r = x0g[b * DIM + lane];
        x1r       = x1g[b * DIM + lane];
        float d0  = x1r - x0r;
        float nrm = sqrtf(waveSum(d0 * d0));
        if (lane == 0) atomicAdd(&ws[1], nrm * (1.0f / BATCH));
        float v  = d0 * dt;
        float nv = nrm * dt;
        v = v / (nv + 1e-8f);
        vel[lane] = v;
        trajr  = x0r;
        fpCur  = x0r;
    }
    __syncthreads();

    unsigned nzflag = 0;

    // ---- pack phase: read raw gamma once, write symmetrized packed copy ----
    if constexpr (PACKED) {
        const float4* g4 = (const float4*)(gam + (size_t)b * DIM * ROWLEN);
        float4 pre = g4[t];                            // prefetch row 0
        for (int i = 0; i < DIM; ++i) {
            {   // scatter f4 into padded staging (scalar stores, conflict-free)
                float* rb = &rowbuf[(i & 1) * DIM * RBSTRIDE];
                float* dst = rb + (t >> 4) * RBSTRIDE + ((t & 15) << 2);
                dst[0] = pre.x; dst[1] = pre.y; dst[2] = pre.z; dst[3] = pre.w;
                nzflag |= (pre.x != 0.f) | (pre.y != 0.f) | (pre.z != 0.f) | (pre.w != 0.f);
            }
            __syncthreads();
            if (i + 1 < DIM) pre = g4[(size_t)(i + 1) * (ROWLEN / 4) + t];
            const float* rb = &rowbuf[(i & 1) * DIM * RBSTRIDE];
            float* prow = pack + ((size_t)b * DIM + i) * NPACK;
            #pragma unroll
            for (int rep = 0; rep < 3; ++rep) {
                int e = t + rep * TPB;
                if (e < NPACK) {
                    uchar2 jk = lut[e];
                    float vsym = rb[jk.x * RBSTRIDE + jk.y];
                    if (jk.x != jk.y) vsym += rb[jk.y * RBSTRIDE + jk.x];
                    prow[e] = vsym;
                }
            }
            __syncthreads();
        }
    }

    const float* mat = PACKED ? pack + (size_t)b * DIM * NPACK
                              : gam  + (size_t)b * DIM * ROWLEN;

    // ---- packed accel: fully-unrolled float4, 2-row pairs ----
    auto accel_packed = [&](const float* vsrc) {
        __syncthreads();                 // vsrc ready; previous wp consumers done
        #pragma unroll
        for (int rep = 0; rep < 3; ++rep) {
            int e = t + rep * TPB;
            if (e < NPACK) {
                uchar2 jk = lut[e];
                wp[e] = vsrc[jk.x] * vsrc[jk.y];
            }
        }
        __syncthreads();
        const float4* wp4 = (const float4*)wp;
        const bool tl = lane < 8;        // tail f4: indices 512..519
        #pragma unroll
        for (int p = 0; p < 2; ++p) {
            const int i0 = (wave << 2) + (p << 1);
            const int i1 = i0 + 1;
            const float4* r0 = (const float4*)(mat + (size_t)i0 * NPACK);
            const float4* r1 = (const float4*)(mat + (size_t)i1 * NPACK);
            float4 g0[8], g1[8];
            #pragma unroll
            for (int u = 0; u < 8; ++u) g0[u] = r0[lane + (u << 6)];
            #pragma unroll
            for (int u = 0; u < 8; ++u) g1[u] = r1[lane + (u << 6)];
            float4 gt0 = make_float4(0.f, 0.f, 0.f, 0.f);
            float4 gt1 = gt0;
            if (tl) { gt0 = r0[512 + lane]; gt1 = r1[512 + lane]; }
            float s0 = 0.f, s1 = 0.f;
            #pragma unroll
            for (int u = 0; u < 8; ++u) {
                float4 w = wp4[lane + (u << 6)];
                s0 += g0[u].x * w.x; s1 += g1[u].x * w.x;
                s0 += g0[u].y * w.y; s1 += g1[u].y * w.y;
                s0 += g0[u].z * w.z; s1 += g1[u].z * w.z;
                s0 += g0[u].w * w.w; s1 += g1[u].w * w.w;
            }
            if (tl) {
                float4 w = wp4[512 + lane];
                s0 += gt0.x * w.x + gt0.y * w.y + gt0.z * w.z + gt0.w * w.w;
                s1 += gt1.x * w.x + gt1.y * w.y + gt1.z * w.z + gt1.w * w.w;
            }
            s0 = waveSum(s0); s1 = waveSum(s1);
            if (lane == 0) { acc[i0] = -s0; acc[i1] = -s1; }
        }
        __syncthreads();
    };

    // ---- raw fallback accel (scalar; only used if ws too small) ----
    auto accel_raw = [&](const float* vsrc, bool doflag) {
        __syncthreads();
        #pragma unroll
        for (int rep = 0; rep < 4; ++rep) {
            int e = t + rep * TPB;
            wp[e] = vsrc[e >> 6] * vsrc[e & 63];
        }
        __syncthreads();
        #pragma unroll
        for (int rr = 0; rr < 4; ++rr) {
            const int i = (wave << 2) + rr;
            const float* mrow = mat + (size_t)i * ROWLEN;
            float s = 0.f;
            for (int u = 0; u < 64; ++u) {
                float g = mrow[lane + (u << 6)];
                if (doflag) nzflag |= (g != 0.f);
                s += g * wp[lane + (u << 6)];
            }
            s = waveSum(s);
            if (lane == 0) acc[i] = -s;
        }
        __syncthreads();
    };

    // ---- RK2 integration ----
    float smooth = 0.f;
    for (int s = 0; s < NSTEPS; ++s) {
        if constexpr (PACKED) accel_packed(vel);
        else                  accel_raw(vel, s == 0);
        if (wave == 0) mvel[lane] = vel[lane] + 0.5f * dt * acc[lane];
        if constexpr (PACKED) accel_packed(mvel);
        else                  accel_raw(mvel, false);
        if (wave == 0) {
            float vnew = vel[lane] + dt * acc[lane];
            vel[lane]  = vnew;
            float fpNext = trajr + dt * vnew;
            trajr = fpNext;
            if (s >= 1) {
                float sec = fpNext - 2.f * fpCur + fpPrev;
                smooth += sqrtf(waveSum(sec * sec));
            }
            fpPrev = fpCur;
            fpCur  = fpNext;
        }
    }

    // ---- nonzero flag ----
    unsigned long long bal = __ballot(nzflag != 0);
    if (lane == 0 && bal) atomicOr((unsigned*)ws + 2, 1u);

    // ---- per-batch geodesic contribution ----
    if (wave == 0) {
        float dl  = trajr - x1r;
        float tgt = sqrtf(waveSum(dl * dl));
        if (lane == 0) atomicAdd(&ws[0], (tgt + 0.1f * smooth) * (1.0f / BATCH));
    }
}

__global__ void finalize_kernel(const float* ws, float* out) {
    unsigned flag = ((const unsigned*)ws)[2];
    out[0] = flag ? ws[0] : ws[1];
}

extern "C" void kernel_launch(void* const* d_in, const int* in_sizes, int n_in,
                              void* d_out, int out_size, void* d_ws, size_t ws_size,
                              hipStream_t stream) {
    const float* x0  = (const float*)d_in[0];   // outputs
    const float* x1  = (const float*)d_in[1];   // targets
    const float* gam = (const float*)d_in[2];   // christoffel_symbols
    float* ws   = (float*)d_ws;
    float* pack = (float*)((char*)d_ws + WS_ACC_FLOATS * sizeof(float));

    const size_t need = WS_ACC_FLOATS * sizeof(float)
                      + (size_t)BATCH * DIM * NPACK * sizeof(float);
    const int use_pack = (ws_size >= need) ? 1 : 0;

    init_ws_kernel<<<1, 64, 0, stream>>>((unsigned*)ws);
    if (use_pack)
        geo_main_kernel<1><<<BATCH, TPB, 0, stream>>>(x0, x1, gam, ws, pack);
    else
        geo_main_kernel<0><<<BATCH, TPB, 0, stream>>>(x0, x1, gam, ws, pack);
    finalize_kernel<<<1, 1, 0, stream>>>(ws, (float*)d_out);
}